// Round 10
// baseline (2602.223 us; speedup 1.0000x reference)
//
#include <hip/hip_runtime.h>
#include <hip/hip_cooperative_groups.h>

namespace cg = cooperative_groups;

// BiCLSTM: S=16,B=4,Cin=32,Co=32,H=W=128. fp32 in/out.
// PERSISTENT cooperative kernel: one launch runs all 16 steps.
//  - B weights resident in LDS (144 KiB, one dir per block), loaded once
//  - c-state resident in registers (block owns its tile for the whole sequence)
//  - h exchanged via ping-pong tile buffers + __threadfence + grid.sync per step
//  - x pre-tiled once to A-operand layout [t][b][tile][pos324][ci32] fp16
#define S_ 16
#define B_ 4
#define H_ 128
#define W_ 128
#define HW_ (H_ * W_)
#define NPOS 324               // 18*18
#define TILE_ELEMS (NPOS * 32) // fp16 elems per tile A-block

typedef __attribute__((ext_vector_type(8))) _Float16 half8;
typedef __attribute__((ext_vector_type(4))) float f32x4;

__device__ __forceinline__ float sigf(float x) { return 1.f / (1.f + __expf(-x)); }
__device__ __forceinline__ float tanhf_(float x) { return 2.f / (1.f + __expf(-2.f * x)) - 1.f; }

__device__ __forceinline__ void gl2lds16(const _Float16* g, _Float16* l) {
    __builtin_amdgcn_global_load_lds(
        (const __attribute__((address_space(1))) unsigned int*)g,
        (__attribute__((address_space(3))) unsigned int*)l, 16, 0, 0);
}

// ---- B-fragment packing: [dir][ks=18][nf=8][lane=64][e=8] fp16 ----
// ks = tap*2 + half; ci = half*32 + (lane>>4)*8 + e; co = nf*16 + (lane&15).
__global__ void prep_pack(const float* __restrict__ Wf, const float* __restrict__ Wb,
                          _Float16* __restrict__ wpk) {
    int id = blockIdx.x * 256 + threadIdx.x;  // 2*18*8*64 = 18432
    if (id >= 18432) return;
    int l = id & 63;
    int nf = (id >> 6) & 7;
    int ks = (id >> 9) % 18;
    int d = id / 9216;
    const float* Wsrc = d ? Wb : Wf;
    int tap = ks >> 1, half = ks & 1;
    int dy = tap / 3, dx = tap - dy * 3;
    int co = nf * 16 + (l & 15);
    _Float16* dst = wpk + (size_t)d * 73728 + ((size_t)(ks * 8 + nf) * 64 + l) * 8;
#pragma unroll
    for (int e = 0; e < 8; ++e) {
        int ci = half * 32 + (l >> 4) * 8 + e;
        dst[e] = (_Float16)Wsrc[((co * 64 + ci) * 3 + dy) * 3 + dx];
    }
}

// ---- One-time x -> tile layout, coalesced: 4 threads/pos, one half8 store each ----
__global__ void prep_xtiles(const float* __restrict__ x, _Float16* __restrict__ xt) {
    int id = blockIdx.x * 256 + threadIdx.x;  // 16*4*64*324*4 = 5,308,416
    if (id >= 16 * 4 * 64 * NPOS * 4) return;
    int cb = id & 3;
    int u = id >> 2;           // [ts][b][tile][pos]
    int pos = u % NPOS;
    int v = u / NPOS;
    int tile = v & 63;
    v >>= 6;
    int b = v & 3;
    int ts = v >> 2;
    int r = pos / 18, cc = pos - r * 18;
    int gy = (tile >> 3) * 16 + r - 1;
    int gx = (tile & 7) * 16 + cc - 1;
    bool inb = ((unsigned)gy < 128u) && ((unsigned)gx < 128u);
    const float* g = x + ((size_t)(ts * 4 + b) * 32 + cb * 8) * HW_ + (size_t)gy * W_ + gx;
    half8 vv;
#pragma unroll
    for (int e = 0; e < 8; ++e)
        vv[e] = inb ? (_Float16)__builtin_nontemporal_load(g + e * HW_) : (_Float16)0.f;
    *(half8*)(xt + (size_t)u * 32 + cb * 8) = vv;
}

// A-frag loader: row band (wq*4+m+dy), col px+dx, kg-th 8-ci chunk.
__device__ __forceinline__ half8 lda(const _Float16* __restrict__ base, int m, int dy,
                                     int dx, int px, int kg, int wq) {
    return *(const half8*)(base + (size_t)(((wq * 4 + m + dy) * 18) + px + dx) * 32 + kg * 8);
}

extern __shared__ _Float16 bsh[];  // 147,456 B: [ks*8+nf][lane][e=8], one dir

// Persistent: grid 256 blocks x 512 threads (1 block/CU).
// bid -> tile (6b) | dir (1b) | bpair (1b). Threads 0-255: b=2*bpair, 256-511: b=2*bpair+1.
__global__ void __launch_bounds__(512, 1)
convlstm_persist(const _Float16* __restrict__ xtiles,
                 _Float16* __restrict__ hb0, _Float16* __restrict__ hb1,
                 const _Float16* __restrict__ wpk,
                 const float* __restrict__ biasf, const float* __restrict__ biasb,
                 float* __restrict__ out) {
    const int bid = blockIdx.x;
    const int tile = bid & 63;
    const int dir = (bid >> 6) & 1;
    const int bpair = bid >> 7;
    const int tid = threadIdx.x;
    const int sub = tid >> 8;
    const int b = bpair * 2 + sub;
    const int dirb = dir * 4 + b;
    const int lane = tid & 63, wq = (tid >> 6) & 3;
    const int px = lane & 15, kg = lane >> 4;

    // Load this dir's full B into LDS once (18 iters x 512 thr x 16B = 147,456 B).
    const _Float16* bw = wpk + (size_t)dir * 73728;
#pragma unroll 1
    for (int i = tid; i < 9216; i += 512)
        gl2lds16(bw + (size_t)i * 8, bsh + (size_t)i * 8);
    __syncthreads();

    const float* bias = dir ? biasb : biasf;
    const int q0 = px;
    float bI[2], bF[2], bO[2], bG[2];
#pragma unroll
    for (int qs = 0; qs < 2; ++qs) {
        bI[qs] = bias[qs * 16 + q0];
        bF[qs] = bias[32 + qs * 16 + q0];
        bO[qs] = bias[64 + qs * 16 + q0];
        bG[qs] = bias[96 + qs * 16 + q0];
    }

    const int gx0 = (tile & 7) * 16, gy0 = (tile >> 3) * 16;
    const int tx = tile & 7, ty_ = tile >> 3;
    const int lx0 = kg * 4;

    float c_reg[4][2][4];
#pragma unroll
    for (int m = 0; m < 4; ++m)
#pragma unroll
        for (int qs = 0; qs < 2; ++qs)
#pragma unroll
            for (int r = 0; r < 4; ++r) c_reg[m][qs][r] = 0.f;

    cg::grid_group grid = cg::this_grid();

#pragma unroll 1
    for (int t = 0; t < S_; ++t) {
        const int ts = dir ? (S_ - 1 - t) : t;
        const _Float16* base_x = xtiles + ((size_t)(ts * 4 + b) * 64 + tile) * TILE_ELEMS;
        const _Float16* hrd = ((t & 1) ? hb0 : hb1);
        _Float16* hwr = ((t & 1) ? hb1 : hb0);
        const _Float16* base_h = hrd + ((size_t)dirb * 64 + tile) * TILE_ELEMS;
        _Float16* hob = hwr + (size_t)dirb * 64 * TILE_ELEMS;
        float* outp = out + ((size_t)(t * 4 + b) * 64 + dir * 32) * HW_;

        f32x4 acc[4][8];
#pragma unroll
        for (int m = 0; m < 4; ++m)
#pragma unroll
            for (int nf = 0; nf < 8; ++nf) acc[m][nf] = (f32x4)(0.f);

        if (t == 0) {
            // x-half only (h(-1)=0).
#pragma unroll 1
            for (int tap = 0; tap < 9; ++tap) {
                int dy = tap / 3, dx = tap - dy * 3;
                half8 a[4];
#pragma unroll
                for (int m = 0; m < 4; ++m) a[m] = lda(base_x, m, dy, dx, px, kg, wq);
#pragma unroll
                for (int nf = 0; nf < 8; ++nf) {
                    half8 bb8 = *(const half8*)(bsh + ((size_t)((tap * 2) * 8 + nf) << 9) + (lane << 3));
#pragma unroll
                    for (int m = 0; m < 4; ++m)
                        acc[m][nf] = __builtin_amdgcn_mfma_f32_16x16x32_f16(a[m], bb8, acc[m][nf], 0, 0, 0);
                }
            }
        } else {
            // ks: even = x-half, odd = h-half. A regs ping-pong; B from resident LDS.
            half8 aP[4], aQ[4];
#pragma unroll
            for (int m = 0; m < 4; ++m) aP[m] = lda(base_x, m, 0, 0, px, kg, wq);

            auto body = [&](int ks, half8(&acur)[4], half8(&anxt)[4]) {
                if (ks < 17) {
                    const int ksn = ks + 1;
                    const int tapn = ksn >> 1;
                    const int dyn_ = tapn / 3, dxn = tapn - dyn_ * 3;
                    const _Float16* an = (ksn & 1) ? base_h : base_x;
#pragma unroll
                    for (int m = 0; m < 4; ++m) anxt[m] = lda(an, m, dyn_, dxn, px, kg, wq);
                }
#pragma unroll
                for (int nf = 0; nf < 8; ++nf) {
                    half8 bb8 = *(const half8*)(bsh + ((size_t)(ks * 8 + nf) << 9) + (lane << 3));
#pragma unroll
                    for (int m = 0; m < 4; ++m)
                        acc[m][nf] = __builtin_amdgcn_mfma_f32_16x16x32_f16(acur[m], bb8, acc[m][nf], 0, 0, 0);
                }
            };
#pragma unroll 1
            for (int ks = 0; ks < 18; ks += 2) {
                body(ks, aP, aQ);
                body(ks + 1, aQ, aP);
            }
        }

        // Epilogue: gates; c in registers; out nt-store; h scatter into write tiles.
#pragma unroll
        for (int m = 0; m < 4; ++m) {
            const int ly = wq * 4 + m;
            const int gy = gy0 + ly;
#pragma unroll
            for (int qs = 0; qs < 2; ++qs) {
                const int q = qs * 16 + q0;
                f32x4 zi = acc[m][qs], zf = acc[m][2 + qs], zo = acc[m][4 + qs], zg = acc[m][6 + qs];
                size_t off = (size_t)q * HW_ + (size_t)gy * W_ + gx0 + lx0;
                f32x4 hn;
#pragma unroll
                for (int r = 0; r < 4; ++r) {
                    float I = sigf(zi[r] + bI[qs]);
                    float F = sigf(zf[r] + bF[qs]);
                    float O = sigf(zo[r] + bO[qs]);
                    float G = tanhf_(zg[r] + bG[qs]);
                    float cnr = F * c_reg[m][qs][r] + I * G;
                    c_reg[m][qs][r] = cnr;
                    hn[r] = O * tanhf_(cnr);
                }
                __builtin_nontemporal_store(hn, (f32x4*)(outp + off));
#pragma unroll
                for (int r = 0; r < 4; ++r) {
                    _Float16 hh = (_Float16)hn[r];
                    int lx = lx0 + r;
                    hob[((size_t)tile) * TILE_ELEMS + (size_t)((ly + 1) * 18 + lx + 1) * 32 + q] = hh;
                    bool Le = (lx == 0) && (tx > 0);
                    bool Re = (lx == 15) && (tx < 7);
                    bool Te = (ly == 0) && (ty_ > 0);
                    bool Be = (ly == 15) && (ty_ < 7);
                    if (Le) hob[((size_t)tile - 1) * TILE_ELEMS + (size_t)((ly + 1) * 18 + 17) * 32 + q] = hh;
                    if (Re) hob[((size_t)tile + 1) * TILE_ELEMS + (size_t)((ly + 1) * 18 + 0) * 32 + q] = hh;
                    if (Te) hob[((size_t)tile - 8) * TILE_ELEMS + (size_t)(17 * 18 + lx + 1) * 32 + q] = hh;
                    if (Be) hob[((size_t)tile + 8) * TILE_ELEMS + (size_t)(0 * 18 + lx + 1) * 32 + q] = hh;
                    if (Te && Le) hob[((size_t)tile - 9) * TILE_ELEMS + (size_t)(17 * 18 + 17) * 32 + q] = hh;
                    if (Te && Re) hob[((size_t)tile - 7) * TILE_ELEMS + (size_t)(17 * 18 + 0) * 32 + q] = hh;
                    if (Be && Le) hob[((size_t)tile + 7) * TILE_ELEMS + (size_t)(0 * 18 + 17) * 32 + q] = hh;
                    if (Be && Re) hob[((size_t)tile + 9) * TILE_ELEMS + (size_t)(0 * 18 + 0) * 32 + q] = hh;
                }
            }
        }

        __threadfence();   // release h writes (L2 writeback) across XCDs
        grid.sync();
        __threadfence();   // acquire: invalidate stale h lines before next read
    }
}

extern "C" void kernel_launch(void* const* d_in, const int* in_sizes, int n_in,
                              void* d_out, int out_size, void* d_ws, size_t ws_size,
                              hipStream_t stream) {
    const float* x  = (const float*)d_in[0];
    const float* Wf = (const float*)d_in[1];
    const float* bf = (const float*)d_in[2];
    const float* Wb = (const float*)d_in[3];
    const float* bb = (const float*)d_in[4];
    float* out = (float*)d_out;
    char* ws = (char*)d_ws;

    const size_t OFF_WPK = 0;                       // 294,912
    const size_t OFF_XT  = 327680;                  // 84,934,656
    const size_t OFF_H0  = OFF_XT + 84934656;       // 10,616,832
    const size_t OFF_H1  = OFF_H0 + 10616832;       // 10,616,832

    _Float16* wpk = (_Float16*)(ws + OFF_WPK);
    _Float16* xt  = (_Float16*)(ws + OFF_XT);
    _Float16* hb0 = (_Float16*)(ws + OFF_H0);
    _Float16* hb1 = (_Float16*)(ws + OFF_H1);

    // Allow 144 KiB dynamic LDS.
    hipFuncSetAttribute((const void*)convlstm_persist,
                        hipFuncAttributeMaxDynamicSharedMemorySize, 147456);

    // Zero h ping-pong buffers (halo slots outside the image must read as 0).
    hipMemsetAsync(ws + OFF_H0, 0, 2u * 10616832u, stream);

    prep_pack<<<dim3(72), dim3(256), 0, stream>>>(Wf, Wb, wpk);
    prep_xtiles<<<dim3(20736), dim3(256), 0, stream>>>(x, xt);

    void* args[] = { (void*)&xt, (void*)&hb0, (void*)&hb1, (void*)&wpk,
                     (void*)&bf, (void*)&bb, (void*)&out };
    hipLaunchCooperativeKernel((const void*)convlstm_persist, dim3(256), dim3(512),
                               args, 147456, stream);
}

// Round 11
// 677.763 us; speedup vs baseline: 3.8394x; 3.8394x over previous
//
#include <hip/hip_runtime.h>

// BiCLSTM: S=16,B=4,Cin=32,Co=32,H=W=128. fp32 in/out.
// FP16 MFMA implicit-GEMM (r8 structure, occupancy-doubled):
//  - 512-thr blocks, 8 waves, each wave 2 rows x 128 co -> acc[2][8]=64 AGPR
//  - __launch_bounds__(512,4): <=128 regs/wave -> 4 waves/SIMD
//  - x pre-tiled [t][b][tile][pos324][ci32] fp16; h scatter into next-step tiles
//  - B staged per-ks via global_load_lds, double-buffered (16 KiB)
#define S_ 16
#define B_ 4
#define H_ 128
#define W_ 128
#define HW_ (H_ * W_)
#define NPOS 324               // 18*18
#define TILE_ELEMS (NPOS * 32) // fp16 elems per tile A-block

typedef __attribute__((ext_vector_type(8))) _Float16 half8;
typedef __attribute__((ext_vector_type(4))) float f32x4;

__device__ __forceinline__ float sigf(float x) { return 1.f / (1.f + __expf(-x)); }
__device__ __forceinline__ float tanhf_(float x) { return 2.f / (1.f + __expf(-2.f * x)) - 1.f; }

__device__ __forceinline__ void gl2lds16(const _Float16* g, _Float16* l) {
    __builtin_amdgcn_global_load_lds(
        (const __attribute__((address_space(1))) unsigned int*)g,
        (__attribute__((address_space(3))) unsigned int*)l, 16, 0, 0);
}

// ---- B-fragment packing: [dir][ks=18][nf=8][lane=64][e=8] fp16 ----
// ks = tap*2 + half; ci = half*32 + (lane>>4)*8 + e; co = nf*16 + (lane&15).
__global__ void prep_pack(const float* __restrict__ Wf, const float* __restrict__ Wb,
                          _Float16* __restrict__ wpk) {
    int id = blockIdx.x * 256 + threadIdx.x;  // 2*18*8*64 = 18432
    if (id >= 18432) return;
    int l = id & 63;
    int nf = (id >> 6) & 7;
    int ks = (id >> 9) % 18;
    int d = id / 9216;
    const float* Wsrc = d ? Wb : Wf;
    int tap = ks >> 1, half = ks & 1;
    int dy = tap / 3, dx = tap - dy * 3;
    int co = nf * 16 + (l & 15);
    _Float16* dst = wpk + (size_t)d * 73728 + ((size_t)(ks * 8 + nf) * 64 + l) * 8;
#pragma unroll
    for (int e = 0; e < 8; ++e) {
        int ci = half * 32 + (l >> 4) * 8 + e;
        dst[e] = (_Float16)Wsrc[((co * 64 + ci) * 3 + dy) * 3 + dx];
    }
}

// ---- One-time x -> tile layout, coalesced: 4 threads/pos, one half8 store each ----
__global__ void prep_xtiles(const float* __restrict__ x, _Float16* __restrict__ xt) {
    int id = blockIdx.x * 256 + threadIdx.x;  // 16*4*64*324*4 = 5,308,416
    if (id >= 16 * 4 * 64 * NPOS * 4) return;
    int cb = id & 3;
    int u = id >> 2;           // [ts][b][tile][pos]
    int pos = u % NPOS;
    int v = u / NPOS;
    int tile = v & 63;
    v >>= 6;
    int b = v & 3;
    int ts = v >> 2;
    int r = pos / 18, cc = pos - r * 18;
    int gy = (tile >> 3) * 16 + r - 1;
    int gx = (tile & 7) * 16 + cc - 1;
    bool inb = ((unsigned)gy < 128u) && ((unsigned)gx < 128u);
    const float* g = x + ((size_t)(ts * 4 + b) * 32 + cb * 8) * HW_ + (size_t)gy * W_ + gx;
    half8 vv;
#pragma unroll
    for (int e = 0; e < 8; ++e)
        vv[e] = inb ? (_Float16)__builtin_nontemporal_load(g + e * HW_) : (_Float16)0.f;
    *(half8*)(xt + (size_t)u * 32 + cb * 8) = vv;
}

// A-frag loader: image row (wq*2+m+dy), col px+dx, kg-th 8-ci chunk.
__device__ __forceinline__ half8 lda(const _Float16* __restrict__ base, int m, int dy,
                                     int dx, int px, int kg, int wq) {
    return *(const half8*)(base + (size_t)(((wq * 2 + m + dy) * 18) + px + dx) * 32 + kg * 8);
}
__device__ __forceinline__ half8 ldb(const _Float16* __restrict__ bw, int ks, int nf, int lane) {
    return *(const half8*)(bw + (size_t)(ks * 8 + nf) * 512 + lane * 8);
}

// One timestep, both directions. grid (64, 8): x = tile, y = dir*4+b. 512 thr, 8 waves.
__global__ __launch_bounds__(512, 4)
void convlstm_step(const _Float16* __restrict__ xtiles,
                   const _Float16* __restrict__ hin,    // read buffer (t-1), tile layout
                   _Float16* __restrict__ hout,         // write buffer (t), tile layout
                   const _Float16* __restrict__ wpk,
                   const float* __restrict__ biasf, const float* __restrict__ biasb,
                   float* __restrict__ cst,             // fp32 c-state [dirb][32][HW]
                   float* __restrict__ out, int t) {
    const int tile = blockIdx.x;
    const int dirb = blockIdx.y;
    const int dir = dirb >> 2, b = dirb & 3;
    const int ts = dir ? (S_ - 1 - t) : t;

    const _Float16* base_x = xtiles + ((size_t)(ts * 4 + b) * 64 + tile) * TILE_ELEMS;
    const _Float16* base_h = hin + ((size_t)dirb * 64 + tile) * TILE_ELEMS;
    _Float16* hob = hout + (size_t)dirb * 64 * TILE_ELEMS;
    const _Float16* bw = wpk + (size_t)dir * 73728;
    const float* bias = dir ? biasb : biasf;
    float* cbase = cst + (size_t)dirb * 32 * HW_;
    float* outp = out + ((size_t)(t * 4 + b) * 64 + dir * 32) * HW_;

    __shared__ alignas(16) _Float16 bsh[2][8][64][8];  // 16 KiB, double-buffered B frags

    const int tid = threadIdx.x;
    const int lane = tid & 63, wq = tid >> 6;          // wq 0..7
    const int px = lane & 15, kg = lane >> 4;

    f32x4 acc[2][8];
#pragma unroll
    for (int m = 0; m < 2; ++m)
#pragma unroll
        for (int nf = 0; nf < 8; ++nf) acc[m][nf] = (f32x4)(0.f);

    if (t == 0) {
        // x-half only (h(-1)=0): direct loads, cold (1/16 of steps).
#pragma unroll 1
        for (int tap = 0; tap < 9; ++tap) {
            int dy = tap / 3, dx = tap - dy * 3;
            half8 a[2];
#pragma unroll
            for (int m = 0; m < 2; ++m) a[m] = lda(base_x, m, dy, dx, px, kg, wq);
#pragma unroll
            for (int nf = 0; nf < 8; ++nf) {
                half8 bb8 = ldb(bw, tap * 2, nf, lane);
#pragma unroll
                for (int m = 0; m < 2; ++m)
                    acc[m][nf] = __builtin_amdgcn_mfma_f32_16x16x32_f16(a[m], bb8, acc[m][nf], 0, 0, 0);
            }
        }
    } else {
        // Pipelined: B(ks) in LDS (wave wq stages frag nf=wq), A(ks) regs ping-pong.
        half8 aP[2], aQ[2];
        {
            gl2lds16(bw + ((size_t)(0 * 8 + wq) * 64 + lane) * 8, &bsh[0][wq][0][0]);
#pragma unroll
            for (int m = 0; m < 2; ++m) aP[m] = lda(base_x, m, 0, 0, px, kg, wq);
        }

        auto body = [&](int ks, half8(&acur)[2], half8(&anxt)[2]) {
            __syncthreads();  // B(ks) staged+visible; buf[(ks+1)&1] reads (iter ks-1) done
            if (ks < 17) {
                const int ksn = ks + 1;
                gl2lds16(bw + ((size_t)(ksn * 8 + wq) * 64 + lane) * 8, &bsh[ksn & 1][wq][0][0]);
                const int tapn = ksn >> 1;
                const int dyn_ = tapn / 3, dxn = tapn - dyn_ * 3;
                const _Float16* an = (ksn & 1) ? base_h : base_x;
#pragma unroll
                for (int m = 0; m < 2; ++m) anxt[m] = lda(an, m, dyn_, dxn, px, kg, wq);
            }
            const _Float16* lb = &bsh[ks & 1][0][0][0];
#pragma unroll
            for (int nf = 0; nf < 8; ++nf) {
                half8 bb8 = *(const half8*)(lb + nf * 512 + lane * 8);
#pragma unroll
                for (int m = 0; m < 2; ++m)
                    acc[m][nf] = __builtin_amdgcn_mfma_f32_16x16x32_f16(acur[m], bb8, acc[m][nf], 0, 0, 0);
            }
        };
#pragma unroll 1
        for (int ks = 0; ks < 18; ks += 2) {
            body(ks, aP, aQ);
            body(ks + 1, aQ, aP);
        }
    }

    // Epilogue. D: col=lane&15 -> co(q within nf-pair), row=(lane>>4)*4+reg -> local x.
    const int q0 = px;
    const int gx0 = (tile & 7) * 16, gy0 = (tile >> 3) * 16;
    const int tx = tile & 7, ty_ = tile >> 3;
    const int lx0 = kg * 4;

    float bI[2], bF[2], bO[2], bG[2];
#pragma unroll
    for (int qs = 0; qs < 2; ++qs) {
        bI[qs] = bias[qs * 16 + q0];
        bF[qs] = bias[32 + qs * 16 + q0];
        bO[qs] = bias[64 + qs * 16 + q0];
        bG[qs] = bias[96 + qs * 16 + q0];
    }
#pragma unroll
    for (int m = 0; m < 2; ++m) {
        const int ly = wq * 2 + m;
        const int gy = gy0 + ly;
#pragma unroll
        for (int qs = 0; qs < 2; ++qs) {
            const int q = qs * 16 + q0;
            f32x4 zi = acc[m][qs], zf = acc[m][2 + qs], zo = acc[m][4 + qs], zg = acc[m][6 + qs];
            size_t off = (size_t)q * HW_ + (size_t)gy * W_ + gx0 + lx0;
            f32x4 cold = (f32x4)(0.f);
            if (t) cold = *(const f32x4*)(cbase + off);
            f32x4 cn, hn;
#pragma unroll
            for (int r = 0; r < 4; ++r) {
                float I = sigf(zi[r] + bI[qs]);
                float F = sigf(zf[r] + bF[qs]);
                float O = sigf(zo[r] + bO[qs]);
                float G = tanhf_(zg[r] + bG[qs]);
                float cnr = F * cold[r] + I * G;
                cn[r] = cnr;
                hn[r] = O * tanhf_(cnr);
            }
            *(f32x4*)(cbase + off) = cn;
            *(f32x4*)(outp + off) = hn;
            // Scatter h(t) fp16 into tile-format write buffer (own + halo neighbors).
#pragma unroll
            for (int r = 0; r < 4; ++r) {
                _Float16 hh = (_Float16)hn[r];
                int lx = lx0 + r;
                hob[((size_t)tile) * TILE_ELEMS + (size_t)((ly + 1) * 18 + lx + 1) * 32 + q] = hh;
                bool Le = (lx == 0) && (tx > 0);
                bool Re = (lx == 15) && (tx < 7);
                bool Te = (ly == 0) && (ty_ > 0);
                bool Be = (ly == 15) && (ty_ < 7);
                if (Le) hob[((size_t)tile - 1) * TILE_ELEMS + (size_t)((ly + 1) * 18 + 17) * 32 + q] = hh;
                if (Re) hob[((size_t)tile + 1) * TILE_ELEMS + (size_t)((ly + 1) * 18 + 0) * 32 + q] = hh;
                if (Te) hob[((size_t)tile - 8) * TILE_ELEMS + (size_t)(17 * 18 + lx + 1) * 32 + q] = hh;
                if (Be) hob[((size_t)tile + 8) * TILE_ELEMS + (size_t)(0 * 18 + lx + 1) * 32 + q] = hh;
                if (Te && Le) hob[((size_t)tile - 9) * TILE_ELEMS + (size_t)(17 * 18 + 17) * 32 + q] = hh;
                if (Te && Re) hob[((size_t)tile - 7) * TILE_ELEMS + (size_t)(17 * 18 + 0) * 32 + q] = hh;
                if (Be && Le) hob[((size_t)tile + 7) * TILE_ELEMS + (size_t)(0 * 18 + 17) * 32 + q] = hh;
                if (Be && Re) hob[((size_t)tile + 9) * TILE_ELEMS + (size_t)(0 * 18 + 0) * 32 + q] = hh;
            }
        }
    }
}

extern "C" void kernel_launch(void* const* d_in, const int* in_sizes, int n_in,
                              void* d_out, int out_size, void* d_ws, size_t ws_size,
                              hipStream_t stream) {
    const float* x  = (const float*)d_in[0];
    const float* Wf = (const float*)d_in[1];
    const float* bf = (const float*)d_in[2];
    const float* Wb = (const float*)d_in[3];
    const float* bb = (const float*)d_in[4];
    float* out = (float*)d_out;
    char* ws = (char*)d_ws;

    const size_t OFF_WPK = 0;                       // 294,912
    const size_t OFF_XT  = 327680;                  // 84,934,656
    const size_t OFF_H0  = OFF_XT + 84934656;       // 10,616,832
    const size_t OFF_H1  = OFF_H0 + 10616832;       // 10,616,832
    const size_t OFF_C   = OFF_H1 + 10616832;       // 16,777,216 (fp32)

    _Float16* wpk = (_Float16*)(ws + OFF_WPK);
    _Float16* xt  = (_Float16*)(ws + OFF_XT);
    _Float16* hb[2] = { (_Float16*)(ws + OFF_H0), (_Float16*)(ws + OFF_H1) };
    float* cst = (float*)(ws + OFF_C);

    // Zero h ping-pong buffers (halo slots outside the image must read as 0).
    hipMemsetAsync(ws + OFF_H0, 0, 2u * 10616832u, stream);

    prep_pack<<<dim3(72), dim3(256), 0, stream>>>(Wf, Wb, wpk);
    prep_xtiles<<<dim3(20736), dim3(256), 0, stream>>>(x, xt);

    for (int t = 0; t < S_; ++t) {
        convlstm_step<<<dim3(64, 8), dim3(512), 0, stream>>>(
            xt, hb[(t + 1) & 1], hb[t & 1], wpk, bf, bb, cst, out, t);
    }
}